// Round 8
// baseline (85.248 us; speedup 1.0000x reference)
//
#include <hip/hip_runtime.h>
#include <math.h>

// EulerRosenbrockModel: B=512, D=256, HID=1024, h=0.01
// out = v + 0.005 * W2 (s ⊙ (W1 v)),  s = 1-t^2, t = tanh(W1 y + b1), v = W2 t + b2
// (Neumann truncation of (I-cJ)^{-1}(I+dJ), exact to ~1e-5 — verified R1-R7.)
//
// R8: 3 dispatches (was 4). Node-count-bound regime (~5us/node on a ~57us
// fixed harness floor), so fuse P+OUT via block-local double-GEMM + fp32
// HW atomics into d_out:
//   K1: Tb = tanh(Y@W1^T + b1)                [512x1024] bf16
//   K2: V  = Tb@W2^T + b2 -> ws Vf AND d_out  [512x256]  fp32 (wave-split-K)
//   K3: per (32b x 64j) slab: P = (1-T^2)⊙(Vf@W1^T); then
//       unsafeAtomicAdd(d_out, 0.005 * P@W2_slice^T)   (16 partials/elem)
// Race-free: K3 reads V only from ws Vf (written once by K2); d_out holds the
// V base (written by K2) and only receives atomic adds in K3. No poison
// reliance, no grid barriers (R5: ~30us each).

#define B_SZ 512
#define D_SZ 256
#define HID_SZ 1024

typedef short short8 __attribute__((ext_vector_type(8)));   // 8 bf16 (4 VGPRs)
typedef float f32x4 __attribute__((ext_vector_type(4)));

__device__ __forceinline__ float bf16_to_f32(unsigned short u) {
    union { unsigned int i; float f; } c; c.i = ((unsigned int)u) << 16; return c.f;
}
__device__ __forceinline__ unsigned short f32_to_bf16(float f) {
    union { float f; unsigned int i; } c; c.f = f;
    unsigned int b = c.i + 0x7FFFu + ((c.i >> 16) & 1u);   // RNE
    return (unsigned short)(b >> 16);
}
__device__ __forceinline__ uint4 pack8(float4 lo, float4 hi) {
    union { unsigned short u[8]; uint4 v; } o;
    o.u[0] = f32_to_bf16(lo.x); o.u[1] = f32_to_bf16(lo.y);
    o.u[2] = f32_to_bf16(lo.z); o.u[3] = f32_to_bf16(lo.w);
    o.u[4] = f32_to_bf16(hi.x); o.u[5] = f32_to_bf16(hi.y);
    o.u[6] = f32_to_bf16(hi.z); o.u[7] = f32_to_bf16(hi.w);
    return o.v;
}

// ==== K1: T[512,1024] = tanh(Y@W1^T + b1), tile 32x64, 256 blocks.
// Whole K=256 panel staged once -> single __syncthreads (verified R7).
__global__ __launch_bounds__(256)
void k1_T(const float* __restrict__ Y, const float* __restrict__ W1,
          const float* __restrict__ b1, unsigned short* __restrict__ Tb)
{
    __shared__ alignas(16) unsigned short As[32][264];  // stride 528B
    __shared__ alignas(16) unsigned short Bs[64][264];
    const int tid = threadIdx.x;
    const int bm = (blockIdx.x & 15) * 32;
    const int bn = (blockIdx.x >> 4) * 64;
    const int wid = tid >> 6, lane = tid & 63;
    const int l16 = lane & 15, quad = lane >> 4;
    const int wm = wid >> 1, wn = wid & 1;

#pragma unroll
    for (int l = 0; l < 4; ++l) {
        int q = l * 256 + tid;
        int row = q >> 5, col = (q & 31) * 8;
        const float* src = &Y[(size_t)(bm + row) * 256 + col];
        float4 lo = *(const float4*)src;
        float4 hi = *(const float4*)(src + 4);
        *(uint4*)&As[row][col] = pack8(lo, hi);
    }
#pragma unroll
    for (int l = 0; l < 8; ++l) {
        int q = l * 256 + tid;
        int row = q >> 5, col = (q & 31) * 8;
        const float* src = &W1[(size_t)(bn + row) * 256 + col];
        float4 lo = *(const float4*)src;
        float4 hi = *(const float4*)(src + 4);
        *(uint4*)&Bs[row][col] = pack8(lo, hi);
    }
    __syncthreads();

    f32x4 acc0 = {0.f,0.f,0.f,0.f}, acc1 = {0.f,0.f,0.f,0.f};
#pragma unroll
    for (int ks = 0; ks < 256; ks += 32) {
        short8 a   = *(const short8*)&As[wm * 16 + l16][ks + quad * 8];
        short8 b0  = *(const short8*)&Bs[wn * 32 + l16][ks + quad * 8];
        short8 b1v = *(const short8*)&Bs[wn * 32 + 16 + l16][ks + quad * 8];
        acc0 = __builtin_amdgcn_mfma_f32_16x16x32_bf16(a, b0,  acc0, 0, 0, 0);
        acc1 = __builtin_amdgcn_mfma_f32_16x16x32_bf16(a, b1v, acc1, 0, 0, 0);
    }
    // C/D layout: col = lane&15, row = quad*4 + r (verified R4-R7)
#pragma unroll
    for (int t2 = 0; t2 < 2; ++t2) {
        f32x4 acc = t2 ? acc1 : acc0;
        int col = bn + wn * 32 + t2 * 16 + l16;
        float bias = b1[col];
#pragma unroll
        for (int r = 0; r < 4; ++r) {
            int row = bm + wm * 16 + quad * 4 + r;
            Tb[(size_t)row * 1024 + col] = f32_to_bf16(tanhf(acc[r] + bias));
        }
    }
}

// ==== K2: V[512,256] = Tb@W2^T + b2, tile 16x32, 256 blocks, wave-split-K.
// Writes V to ws Vf (stable copy for K3) AND d_out (atomic accumulation base).
__global__ __launch_bounds__(256)
void k2_V(const unsigned short* __restrict__ Tb, const float* __restrict__ W2,
          const float* __restrict__ b2, float* __restrict__ Vf,
          float* __restrict__ OUT)
{
    __shared__ alignas(16) unsigned short As[16][520];
    __shared__ alignas(16) unsigned short Bs[32][520];
    __shared__ alignas(16) float red[64][34];
    const int tid = threadIdx.x;
    const int bm = (blockIdx.x & 31) * 16;
    const int bn = (blockIdx.x >> 5) * 32;
    const int wid = tid >> 6, lane = tid & 63;
    const int l16 = lane & 15, quad = lane >> 4;
    const int woff = wid * 128;

    f32x4 acc0 = {0.f,0.f,0.f,0.f}, acc1 = {0.f,0.f,0.f,0.f};

#pragma unroll
    for (int p = 0; p < 2; ++p) {
#pragma unroll
        for (int l = 0; l < 4; ++l) {
            int q = l * 256 + tid;
            int row = q >> 6, col = (q & 63) * 8;
            *(uint4*)&As[row][col] =
                *(const uint4*)&Tb[(size_t)(bm + row) * 1024 + p * 512 + col];
        }
#pragma unroll
        for (int l = 0; l < 8; ++l) {
            int q = l * 256 + tid;
            int row = q >> 6, col = (q & 63) * 8;
            const float* src = &W2[(size_t)(bn + row) * 1024 + p * 512 + col];
            float4 lo = *(const float4*)src;
            float4 hi = *(const float4*)(src + 4);
            *(uint4*)&Bs[row][col] = pack8(lo, hi);
        }
        __syncthreads();
#pragma unroll
        for (int ks = 0; ks < 128; ks += 32) {
            short8 a   = *(const short8*)&As[l16][woff + ks + quad * 8];
            short8 b0  = *(const short8*)&Bs[l16][woff + ks + quad * 8];
            short8 b1v = *(const short8*)&Bs[16 + l16][woff + ks + quad * 8];
            acc0 = __builtin_amdgcn_mfma_f32_16x16x32_bf16(a, b0,  acc0, 0, 0, 0);
            acc1 = __builtin_amdgcn_mfma_f32_16x16x32_bf16(a, b1v, acc1, 0, 0, 0);
        }
        __syncthreads();
    }
#pragma unroll
    for (int r = 0; r < 4; ++r) {
        red[wid * 16 + quad * 4 + r][l16]      = acc0[r];
        red[wid * 16 + quad * 4 + r][16 + l16] = acc1[r];
    }
    __syncthreads();
    {
        int m = tid >> 4, n = (tid & 15) * 2;
        float2 s = {0.f, 0.f};
#pragma unroll
        for (int w = 0; w < 4; ++w) {
            float2 pv = *(const float2*)&red[w * 16 + m][n];
            s.x += pv.x; s.y += pv.y;
        }
        int gm = bm + m, gn = bn + n;
        size_t idx = (size_t)gm * 256 + gn;
        float2 bb = *(const float2*)&b2[gn];
        float2 v = {s.x + bb.x, s.y + bb.y};
        *(float2*)&Vf[idx]  = v;
        *(float2*)&OUT[idx] = v;   // base for K3's atomic adds
    }
}

// ==== K3: per-slab fused P + OUT. 256 blocks: bm=(blk&15)*32 b-rows,
// jg=blk>>4 -> j-cols jg*64..+64.
//   GEMM1: P[32x64] = (1-T^2) ⊙ (Vf@W1_rows^T)   (M=32,N=64,K=256)
//   GEMM2: U[32x256] = P @ W2[:, jslice]^T        (M=32,N=256,K=64)
//   unsafeAtomicAdd(OUT, 0.005*U)
__global__ __launch_bounds__(256)
void k3_PO(const float* __restrict__ Vf, const float* __restrict__ W1,
           const unsigned short* __restrict__ Tb, const float* __restrict__ W2,
           float* __restrict__ OUT)
{
    __shared__ alignas(16) char smem[50688];
    unsigned short (*As)[264] = (unsigned short(*)[264])smem;            // 32 rows, ph1
    unsigned short (*Bs)[264] = (unsigned short(*)[264])(smem + 16896);  // 64 rows, ph1
    unsigned short (*Ps)[72]  = (unsigned short(*)[72])smem;             // 32 rows, ph2
    unsigned short (*Ws)[72]  = (unsigned short(*)[72])(smem + 4608);    // 256 rows, ph2

    const int tid = threadIdx.x;
    const int bm = (blockIdx.x & 15) * 32;
    const int jbase = (blockIdx.x >> 4) * 64;
    const int wid = tid >> 6, lane = tid & 63;
    const int l16 = lane & 15, quad = lane >> 4;
    const int wm = wid >> 1, wn = wid & 1;

    // ---- phase 1 staging: A = Vf (fp32->bf16), B = W1 rows jbase..+64
#pragma unroll
    for (int l = 0; l < 4; ++l) {
        int q = l * 256 + tid;
        int row = q >> 5, col = (q & 31) * 8;
        const float* src = &Vf[(size_t)(bm + row) * 256 + col];
        float4 lo = *(const float4*)src;
        float4 hi = *(const float4*)(src + 4);
        *(uint4*)&As[row][col] = pack8(lo, hi);
    }
#pragma unroll
    for (int l = 0; l < 8; ++l) {
        int q = l * 256 + tid;
        int row = q >> 5, col = (q & 31) * 8;
        const float* src = &W1[(size_t)(jbase + row) * 256 + col];
        float4 lo = *(const float4*)src;
        float4 hi = *(const float4*)(src + 4);
        *(uint4*)&Bs[row][col] = pack8(lo, hi);
    }
    __syncthreads();

    // ---- GEMM1: P tile
    f32x4 acc0 = {0.f,0.f,0.f,0.f}, acc1 = {0.f,0.f,0.f,0.f};
#pragma unroll
    for (int ks = 0; ks < 256; ks += 32) {
        short8 a   = *(const short8*)&As[wm * 16 + l16][ks + quad * 8];
        short8 b0  = *(const short8*)&Bs[wn * 32 + l16][ks + quad * 8];
        short8 b1v = *(const short8*)&Bs[wn * 32 + 16 + l16][ks + quad * 8];
        acc0 = __builtin_amdgcn_mfma_f32_16x16x32_bf16(a, b0,  acc0, 0, 0, 0);
        acc1 = __builtin_amdgcn_mfma_f32_16x16x32_bf16(a, b1v, acc1, 0, 0, 0);
    }
    __syncthreads();   // done reading As/Bs; safe to overwrite with Ps/Ws

    // ---- epilogue1: s-multiply, write P (bf16) into LDS in A-operand layout
#pragma unroll
    for (int t2 = 0; t2 < 2; ++t2) {
        f32x4 acc = t2 ? acc1 : acc0;
        int jcol = wn * 32 + t2 * 16 + l16;           // j within 64
#pragma unroll
        for (int r = 0; r < 4; ++r) {
            int brow = wm * 16 + quad * 4 + r;        // b within 32
            float tt = bf16_to_f32(Tb[(size_t)(bm + brow) * 1024 + jbase + jcol]);
            Ps[brow][jcol] = f32_to_bf16(acc[r] * (1.f - tt * tt));
        }
    }
    // ---- phase 2 staging: W2 slice [256 i][64 j] fp32 -> bf16
#pragma unroll
    for (int l = 0; l < 16; ++l) {
        int u = l * 256 + tid;
        int i = u >> 4, j4 = (u & 15) * 4;            // 16 threads cover one i-row
        float4 v = *(const float4*)&W2[(size_t)i * 1024 + jbase + j4];
        Ws[i][j4 + 0] = f32_to_bf16(v.x);
        Ws[i][j4 + 1] = f32_to_bf16(v.y);
        Ws[i][j4 + 2] = f32_to_bf16(v.z);
        Ws[i][j4 + 3] = f32_to_bf16(v.w);
    }
    __syncthreads();

    // ---- GEMM2: U = P @ W2slice^T  (M=32,N=256 -> wave owns 64 i-cols, K=64)
    f32x4 acc2[2][4];
#pragma unroll
    for (int mt = 0; mt < 2; ++mt)
#pragma unroll
        for (int nt = 0; nt < 4; ++nt) acc2[mt][nt] = (f32x4){0.f,0.f,0.f,0.f};
#pragma unroll
    for (int ks = 0; ks < 64; ks += 32) {
#pragma unroll
        for (int mt = 0; mt < 2; ++mt) {
            short8 a = *(const short8*)&Ps[mt * 16 + l16][ks + quad * 8];
#pragma unroll
            for (int nt = 0; nt < 4; ++nt) {
                short8 b = *(const short8*)&Ws[wid * 64 + nt * 16 + l16][ks + quad * 8];
                acc2[mt][nt] = __builtin_amdgcn_mfma_f32_16x16x32_bf16(a, b, acc2[mt][nt], 0, 0, 0);
            }
        }
    }
    // ---- epilogue2: OUT += 0.005 * U  (HW fp32 atomics; 16 partials/element)
#pragma unroll
    for (int mt = 0; mt < 2; ++mt)
#pragma unroll
        for (int nt = 0; nt < 4; ++nt) {
            int col = wid * 64 + nt * 16 + l16;       // i
#pragma unroll
            for (int r = 0; r < 4; ++r) {
                int row = bm + mt * 16 + quad * 4 + r;
                unsafeAtomicAdd(&OUT[(size_t)row * 256 + col],
                                0.005f * acc2[mt][nt][r]);
            }
        }
}

extern "C" void kernel_launch(void* const* d_in, const int* in_sizes, int n_in,
                              void* d_out, int out_size, void* d_ws, size_t ws_size,
                              hipStream_t stream) {
    const float* Y  = (const float*)d_in[0];  // (512, 256)
    const float* W1 = (const float*)d_in[1];  // (1024, 256)
    const float* b1 = (const float*)d_in[2];  // (1024,)
    const float* W2 = (const float*)d_in[3];  // (256, 1024)
    const float* b2 = (const float*)d_in[4];  // (256,)
    float* OUT = (float*)d_out;               // (512, 256)

    unsigned short* Tb = (unsigned short*)d_ws;               // [512][1024] bf16, 1 MB
    float* Vf = (float*)(Tb + (size_t)B_SZ * HID_SZ);         // [512][256] fp32, 512 KB

    k1_T<<<256, 256, 0, stream>>>(Y, W1, b1, Tb);
    k2_V<<<256, 256, 0, stream>>>(Tb, W2, b2, Vf, OUT);
    k3_PO<<<256, 256, 0, stream>>>(Vf, W1, Tb, W2, OUT);
}

// Round 9
// 78.590 us; speedup vs baseline: 1.0847x; 1.0847x over previous
//
#include <hip/hip_runtime.h>
#include <math.h>

// EulerRosenbrockModel: B=512, D=256, HID=1024, h=0.01
// out = v + 0.005 * W2 (s ⊙ (W1 v)),  s = 1-t^2, t = tanh(W1 y + b1), v = W2 t + b2
// (Neumann truncation of (I-cJ)^{-1}(I+dJ), exact to ~1e-5 — verified R1-R8.)
//
// R9 = R7 (best: 78.4us) minus the Vb buffer. 4 dispatches, 256 blocks (1/CU):
//   K1: Tb = tanh(Y@W1^T + b1)            [512x1024] bf16  (Y,W1 fp32->bf16 inline)
//   K2: Vf = Tb@W2^T + b2                 [512x256]  fp32  (wave-split-K)
//   K3: Pb = (1-Tb^2) ⊙ (Vf@W1^T)         [512x1024] bf16  (Vf converted inline)
//   K4: OUT = Vf + 0.005*(Pb@W2^T)        [512x256]  fp32
// Structural floor evidence: going below 4 nodes failed 3 independent ways —
// R5 grid barriers (+30us each: agent-scope fence = per-XCD L2 writeback),
// R6 M=W1@W2 precompute (+1.6 GF, L2-bound), R8 atomic fusion (+7us: heavier
// K3 + 16-way atomic contention). Remaining time = ~57us harness floor
// (268MB ws poison fill, measured in-window) + 4 kernels (~3us each, compute
// floor ~3us total) + 3 dispatch gaps (~4-5us each).

#define B_SZ 512
#define D_SZ 256
#define HID_SZ 1024

typedef short short8 __attribute__((ext_vector_type(8)));   // 8 bf16 (4 VGPRs)
typedef float f32x4 __attribute__((ext_vector_type(4)));

__device__ __forceinline__ float bf16_to_f32(unsigned short u) {
    union { unsigned int i; float f; } c; c.i = ((unsigned int)u) << 16; return c.f;
}
__device__ __forceinline__ unsigned short f32_to_bf16(float f) {
    union { float f; unsigned int i; } c; c.f = f;
    unsigned int b = c.i + 0x7FFFu + ((c.i >> 16) & 1u);   // RNE
    return (unsigned short)(b >> 16);
}
__device__ __forceinline__ uint4 pack8(float4 lo, float4 hi) {
    union { unsigned short u[8]; uint4 v; } o;
    o.u[0] = f32_to_bf16(lo.x); o.u[1] = f32_to_bf16(lo.y);
    o.u[2] = f32_to_bf16(lo.z); o.u[3] = f32_to_bf16(lo.w);
    o.u[4] = f32_to_bf16(hi.x); o.u[5] = f32_to_bf16(hi.y);
    o.u[6] = f32_to_bf16(hi.z); o.u[7] = f32_to_bf16(hi.w);
    return o.v;
}

// ==== K1/K3: C[512,1024] = A[512,256] @ W1[1024,256]^T, tile 32x64, 256 blocks.
// A is fp32 (Y or Vf), converted to bf16 during LDS staging. Whole K=256 panel
// staged once -> single __syncthreads before the MFMA loop (verified R7).
enum { EPI_T = 0, EPI_P = 1 };
template<int EPI>
__global__ __launch_bounds__(256)
void gemm_h(const float* __restrict__ Afp,          // Y (EPI_T) or Vf (EPI_P)
            const float* __restrict__ W1,
            const float* __restrict__ b1,
            const unsigned short* __restrict__ Tin, // EPI_P: Tb
            unsigned short* __restrict__ Ob)        // Tb or Pb
{
    __shared__ alignas(16) unsigned short As[32][264];  // stride 528B
    __shared__ alignas(16) unsigned short Bs[64][264];
    const int tid = threadIdx.x;
    const int bm = (blockIdx.x & 15) * 32;
    const int bn = (blockIdx.x >> 4) * 64;
    const int wid = tid >> 6, lane = tid & 63;
    const int l16 = lane & 15, quad = lane >> 4;
    const int wm = wid >> 1, wn = wid & 1;

    // stage A: 32 rows x 256 k, fp32 -> bf16 (4 units of 8 elems per thread)
#pragma unroll
    for (int l = 0; l < 4; ++l) {
        int q = l * 256 + tid;
        int row = q >> 5, col = (q & 31) * 8;
        const float* src = &Afp[(size_t)(bm + row) * 256 + col];
        float4 lo = *(const float4*)src;
        float4 hi = *(const float4*)(src + 4);
        *(uint4*)&As[row][col] = pack8(lo, hi);
    }
    // stage B: 64 rows x 256 k, fp32 W1 -> bf16 (8 units per thread)
#pragma unroll
    for (int l = 0; l < 8; ++l) {
        int q = l * 256 + tid;
        int row = q >> 5, col = (q & 31) * 8;
        const float* src = &W1[(size_t)(bn + row) * 256 + col];
        float4 lo = *(const float4*)src;
        float4 hi = *(const float4*)(src + 4);
        *(uint4*)&Bs[row][col] = pack8(lo, hi);
    }
    __syncthreads();

    f32x4 acc0 = {0.f,0.f,0.f,0.f}, acc1 = {0.f,0.f,0.f,0.f};
#pragma unroll
    for (int ks = 0; ks < 256; ks += 32) {
        short8 a   = *(const short8*)&As[wm * 16 + l16][ks + quad * 8];
        short8 b0  = *(const short8*)&Bs[wn * 32 + l16][ks + quad * 8];
        short8 b1v = *(const short8*)&Bs[wn * 32 + 16 + l16][ks + quad * 8];
        acc0 = __builtin_amdgcn_mfma_f32_16x16x32_bf16(a, b0,  acc0, 0, 0, 0);
        acc1 = __builtin_amdgcn_mfma_f32_16x16x32_bf16(a, b1v, acc1, 0, 0, 0);
    }
    // C/D layout: col = lane&15, row = quad*4 + r (verified R4-R8)
#pragma unroll
    for (int t2 = 0; t2 < 2; ++t2) {
        f32x4 acc = t2 ? acc1 : acc0;
        int col = bn + wn * 32 + t2 * 16 + l16;
        float bias = 0.f;
        if constexpr (EPI == EPI_T) bias = b1[col];
#pragma unroll
        for (int r = 0; r < 4; ++r) {
            int row = bm + wm * 16 + quad * 4 + r;
            float v = acc[r];
            float o;
            if constexpr (EPI == EPI_T) {
                o = tanhf(v + bias);
            } else {
                float tt = bf16_to_f32(Tin[(size_t)row * 1024 + col]);
                o = v * (1.f - tt * tt);
            }
            Ob[(size_t)row * 1024 + col] = f32_to_bf16(o);
        }
    }
}

// ==== K2/K4: C[512,256] = A[512,1024] @ W2[256,1024]^T, tile 16x32, 256 blocks.
// Wave w owns K chunk w*256..+256; K staged in 2 phases of 512 (wave slice
// 128/phase); cross-wave LDS reduction (verified R4-R8).
enum { EPI_V = 0, EPI_O = 1 };
template<int EPI>
__global__ __launch_bounds__(256)
void gemm_d(const unsigned short* __restrict__ Ab,  // Tb or Pb, [512][1024] bf16
            const float* __restrict__ W2,           // [256][1024] fp32
            const float* __restrict__ b2,
            const float* __restrict__ Vin,          // EPI_O
            float* __restrict__ Vf_out,             // EPI_V
            float* __restrict__ OUT)                // EPI_O
{
    __shared__ alignas(16) unsigned short As[16][520];
    __shared__ alignas(16) unsigned short Bs[32][520];
    __shared__ alignas(16) float red[64][34];
    const int tid = threadIdx.x;
    const int bm = (blockIdx.x & 31) * 16;
    const int bn = (blockIdx.x >> 5) * 32;
    const int wid = tid >> 6, lane = tid & 63;
    const int l16 = lane & 15, quad = lane >> 4;
    const int woff = wid * 128;   // wave's in-phase LDS k-offset

    f32x4 acc0 = {0.f,0.f,0.f,0.f}, acc1 = {0.f,0.f,0.f,0.f};

#pragma unroll
    for (int p = 0; p < 2; ++p) {
        // stage A: 16 rows x 512 k bf16 (4 units/thread, direct copy)
#pragma unroll
        for (int l = 0; l < 4; ++l) {
            int q = l * 256 + tid;
            int row = q >> 6, col = (q & 63) * 8;
            *(uint4*)&As[row][col] =
                *(const uint4*)&Ab[(size_t)(bm + row) * 1024 + p * 512 + col];
        }
        // stage B: 32 rows x 512 k, fp32 W2 -> bf16 (8 units/thread)
#pragma unroll
        for (int l = 0; l < 8; ++l) {
            int q = l * 256 + tid;
            int row = q >> 6, col = (q & 63) * 8;
            const float* src = &W2[(size_t)(bn + row) * 1024 + p * 512 + col];
            float4 lo = *(const float4*)src;
            float4 hi = *(const float4*)(src + 4);
            *(uint4*)&Bs[row][col] = pack8(lo, hi);
        }
        __syncthreads();
#pragma unroll
        for (int ks = 0; ks < 128; ks += 32) {
            short8 a   = *(const short8*)&As[l16][woff + ks + quad * 8];
            short8 b0  = *(const short8*)&Bs[l16][woff + ks + quad * 8];
            short8 b1v = *(const short8*)&Bs[16 + l16][woff + ks + quad * 8];
            acc0 = __builtin_amdgcn_mfma_f32_16x16x32_bf16(a, b0,  acc0, 0, 0, 0);
            acc1 = __builtin_amdgcn_mfma_f32_16x16x32_bf16(a, b1v, acc1, 0, 0, 0);
        }
        __syncthreads();
    }
#pragma unroll
    for (int r = 0; r < 4; ++r) {
        red[wid * 16 + quad * 4 + r][l16]      = acc0[r];
        red[wid * 16 + quad * 4 + r][16 + l16] = acc1[r];
    }
    __syncthreads();
    {
        int m = tid >> 4, n = (tid & 15) * 2;
        float2 s = {0.f, 0.f};
#pragma unroll
        for (int w = 0; w < 4; ++w) {
            float2 pv = *(const float2*)&red[w * 16 + m][n];
            s.x += pv.x; s.y += pv.y;
        }
        int gm = bm + m, gn = bn + n;
        size_t idx = (size_t)gm * 256 + gn;
        if constexpr (EPI == EPI_V) {
            float2 bb = *(const float2*)&b2[gn];
            float2 v = {s.x + bb.x, s.y + bb.y};
            *(float2*)&Vf_out[idx] = v;
        } else {
            float2 vv = *(const float2*)&Vin[idx];
            float2 o = {fmaf(0.005f, s.x, vv.x), fmaf(0.005f, s.y, vv.y)};
            *(float2*)&OUT[idx] = o;
        }
    }
}

extern "C" void kernel_launch(void* const* d_in, const int* in_sizes, int n_in,
                              void* d_out, int out_size, void* d_ws, size_t ws_size,
                              hipStream_t stream) {
    const float* Y  = (const float*)d_in[0];  // (512, 256)
    const float* W1 = (const float*)d_in[1];  // (1024, 256)
    const float* b1 = (const float*)d_in[2];  // (1024,)
    const float* W2 = (const float*)d_in[3];  // (256, 1024)
    const float* b2 = (const float*)d_in[4];  // (256,)
    float* OUT = (float*)d_out;               // (512, 256)

    unsigned short* Tb = (unsigned short*)d_ws;        // [512][1024] bf16, 1 MB
    unsigned short* Pb = Tb + (size_t)B_SZ * HID_SZ;   // [512][1024] bf16, 1 MB
    float*          Vf = (float*)(Pb + (size_t)B_SZ * HID_SZ);  // [512][256] fp32

    gemm_h<EPI_T><<<256, 256, 0, stream>>>(Y,  W1, b1, nullptr, Tb);
    gemm_d<EPI_V><<<256, 256, 0, stream>>>(Tb, W2, b2, nullptr, Vf, nullptr);
    gemm_h<EPI_P><<<256, 256, 0, stream>>>(Vf, W1, nullptr, Tb, Pb);
    gemm_d<EPI_O><<<256, 256, 0, stream>>>(Pb, W2, nullptr, Vf, nullptr, OUT);
}